// Round 5
// baseline (279.180 us; speedup 1.0000x reference)
//
#include <hip/hip_runtime.h>
#include <math.h>
#include <stdint.h>

#define C         128
#define KCODES    1024
#define TPB       256
#define ROWS_PB   64
#define NCHUNK    32
#define NCHUNKS   16                     // per 512-code partition
#define BSTRIDE   272                    // padded LDS row stride (bytes)
#define HLBYTES   (NCHUNK * BSTRIDE)     // 8704
#define PARTBYTES (2 * HLBYTES)          // 17408 (hi + lo)
#define EPS_TRIG  0.25f

typedef __attribute__((ext_vector_type(8))) short bf16x8_t;
typedef __attribute__((ext_vector_type(4))) float f32x4_t;
#define MFMA_BF16 __builtin_amdgcn_mfma_f32_16x16x32_bf16

static __device__ __forceinline__ uint32_t bf16_rne(float f) {
    uint32_t u = __float_as_uint(f);
    return (u + 0x7FFFu + ((u >> 16) & 1u)) >> 16;
}

// ---------------- prep: split codebook into bf16 hi/lo ----------------
__global__ void cb_split_kernel(const float* __restrict__ cb,
                                uint16_t* __restrict__ cbh,
                                uint16_t* __restrict__ cbl) {
    int i = blockIdx.x * blockDim.x + threadIdx.x;
    if (i >= KCODES * C) return;
    float f = cb[i];
    uint32_t h = bf16_rne(f);
    float lo = f - __uint_as_float(h << 16);
    cbh[i] = (uint16_t)h;
    cbl[i] = (uint16_t)bf16_rne(lo);
}

// ---------------- prep: ||c||^2 (R1 arithmetic order) ----------------
__global__ void cbsq_kernel(const float* __restrict__ cb, float* __restrict__ cbsq) {
    const int k = blockIdx.x * blockDim.x + threadIdx.x;
    if (k >= KCODES) return;
    const float4* cp = (const float4*)(cb + (size_t)k * C);
    float sx = 0.f, sy = 0.f, sz = 0.f, sw = 0.f;
    #pragma unroll
    for (int i = 0; i < C / 4; ++i) {
        float4 v = cp[i];
        sx += v.x * v.x; sy += v.y * v.y;
        sz += v.z * v.z; sw += v.w * v.w;
    }
    cbsq[k] = (sx + sy) + (sz + sw);
}

// ---------------- main: 64 rows x 1024 codes per block ----------------
// 4 waves: (rowwave 0/1) x (code-partition 0/1). Exact fp32 top-2 per lane,
// lexicographic merges, fp64 near-tie re-decide (R1/R2/R3-proven logic).
__global__ __launch_bounds__(TPB, 4)
void vq_mfma3_kernel(const float* __restrict__ x,
                     const float* __restrict__ cb,
                     const uint16_t* __restrict__ cbh,
                     const uint16_t* __restrict__ cbl,
                     const float* __restrict__ cq,
                     float* __restrict__ out_codes,
                     float* __restrict__ out_fidx,
                     float* __restrict__ out_idx,
                     float* __restrict__ out_dist,
                     int rows)
{
    __shared__ __align__(16) uint8_t s_buf[2 * PARTBYTES];   // 34816 B
    __shared__ float  s_cq[2][NCHUNK];
    __shared__ float4 s_res[2][ROWS_PB];
    __shared__ int    s_kf[ROWS_PB];

    const int t    = threadIdx.x;
    const int lane = t & 63;
    const int w    = t >> 6;
    const int part = w >> 1;        // code partition 0/1 (512 codes each)
    const int rw   = w & 1;         // row-wave 0/1 (32 rows each)
    const int ln   = lane & 15;
    const int quad = lane >> 4;
    const int rowblock = blockIdx.x * ROWS_PB;

    // ---- A fragments (bf16 hi/lo) straight from global, in-register split ----
    bf16x8_t ah[2][4], al[2][4];
    #pragma unroll
    for (int g = 0; g < 2; ++g) {
        int rowg = rowblock + rw * 32 + g * 16 + ln;
        rowg = rowg < rows ? rowg : rows - 1;
        const float* xp = x + (size_t)rowg * C + quad * 8;
        #pragma unroll
        for (int kk = 0; kk < 4; ++kk) {
            float4 v0 = *(const float4*)(xp + kk * 32);
            float4 v1 = *(const float4*)(xp + kk * 32 + 4);
            float f[8] = {v0.x, v0.y, v0.z, v0.w, v1.x, v1.y, v1.z, v1.w};
            bf16x8_t hv, lv;
            #pragma unroll
            for (int j = 0; j < 8; ++j) {
                uint32_t hb = bf16_rne(f[j]);
                hv[j] = (short)hb;
                float r = f[j] - __uint_as_float(hb << 16);
                lv[j] = (short)bf16_rne(r);
            }
            ah[g][kk] = hv; al[g][kk] = lv;
        }
    }

    // ---- exact fp32 top-2 state per (rowgroup, acc-reg) slot ----
    float v1[2][4], v2[2][4];
    int   k1[2][4], k2[2][4];
    #pragma unroll
    for (int g = 0; g < 2; ++g)
        #pragma unroll
        for (int r = 0; r < 4; ++r) {
            v1[g][r] = INFINITY; v2[g][r] = INFINITY;
            k1[g][r] = 0x7fffffff; k2[g][r] = 0x7fffffff;
        }

    const int kbase_lane = part * 512 + ln;

    #pragma unroll 1
    for (int chn = 0; chn < NCHUNKS; ++chn) {
        // ---- stage both partitions' 32-code chunks (hi+lo), 2 rounds of 4 uint4 ----
        {
            uint4 ld[4];
            #pragma unroll
            for (int i = 0; i < 4; ++i) {
                int u = t + i * TPB;
                int pt_ = u >> 10, hl = (u >> 9) & 1, code = (u >> 4) & 31, gq = u & 15;
                const uint4* srcb = hl ? (const uint4*)cbl : (const uint4*)cbh;
                ld[i] = srcb[((size_t)(pt_ * 512 + chn * 32 + code) << 4) + gq];
            }
            __syncthreads();   // previous chunk fully consumed
            #pragma unroll
            for (int i = 0; i < 4; ++i) {
                int u = t + i * TPB;
                int pt_ = u >> 10, hl = (u >> 9) & 1, code = (u >> 4) & 31, gq = u & 15;
                *(uint4*)(s_buf + pt_ * PARTBYTES + hl * HLBYTES + code * BSTRIDE + gq * 16) = ld[i];
            }
            #pragma unroll
            for (int i = 4; i < 8; ++i) {
                int u = t + i * TPB;
                int pt_ = u >> 10, hl = (u >> 9) & 1, code = (u >> 4) & 31, gq = u & 15;
                const uint4* srcb = hl ? (const uint4*)cbl : (const uint4*)cbh;
                ld[i - 4] = srcb[((size_t)(pt_ * 512 + chn * 32 + code) << 4) + gq];
            }
            #pragma unroll
            for (int i = 4; i < 8; ++i) {
                int u = t + i * TPB;
                int pt_ = u >> 10, hl = (u >> 9) & 1, code = (u >> 4) & 31, gq = u & 15;
                *(uint4*)(s_buf + pt_ * PARTBYTES + hl * HLBYTES + code * BSTRIDE + gq * 16) = ld[i - 4];
            }
            if (t < 64) s_cq[t >> 5][t & 31] = cq[(t >> 5) * 512 + chn * 32 + (t & 31)];
        }
        __syncthreads();

        // ---- compute: 2 ct-tiles of 16 codes ----
        const uint8_t* bb = s_buf + part * PARTBYTES + (size_t)ln * BSTRIDE + quad * 16;
        #pragma unroll
        for (int ct = 0; ct < 2; ++ct) {
            const uint8_t* bh_p = bb + (size_t)ct * 16 * BSTRIDE;
            const uint8_t* bl_p = bh_p + HLBYTES;
            f32x4_t acc0 = {0.f, 0.f, 0.f, 0.f};
            f32x4_t acc1 = {0.f, 0.f, 0.f, 0.f};
            #pragma unroll
            for (int kk = 0; kk < 4; ++kk) {
                bf16x8_t bh = *(const bf16x8_t*)(bh_p + kk * 64);
                bf16x8_t bl = *(const bf16x8_t*)(bl_p + kk * 64);
                acc0 = MFMA_BF16(ah[0][kk], bh, acc0, 0, 0, 0);
                acc1 = MFMA_BF16(ah[1][kk], bh, acc1, 0, 0, 0);
                acc0 = MFMA_BF16(al[0][kk], bh, acc0, 0, 0, 0);
                acc1 = MFMA_BF16(al[1][kk], bh, acc1, 0, 0, 0);
                acc0 = MFMA_BF16(ah[0][kk], bl, acc0, 0, 0, 0);
                acc1 = MFMA_BF16(ah[1][kk], bl, acc1, 0, 0, 0);
            }
            const float cqv = s_cq[part][ct * 16 + ln];
            const int   kc  = kbase_lane + chn * 32 + ct * 16;
            #pragma unroll
            for (int g = 0; g < 2; ++g)
                #pragma unroll
                for (int r = 0; r < 4; ++r) {
                    float s_ = fmaf(-2.f, (g ? acc1 : acc0)[r], cqv);
                    bool c1 = s_ < v1[g][r];
                    bool c2 = s_ < v2[g][r];
                    v2[g][r] = c1 ? v1[g][r] : (c2 ? s_ : v2[g][r]);
                    k2[g][r] = c1 ? k1[g][r] : (c2 ? kc : k2[g][r]);
                    v1[g][r] = c1 ? s_ : v1[g][r];
                    k1[g][r] = c1 ? kc : k1[g][r];
                }
        }
    }

    // ---- butterfly top-2 merge across the 16 lanes of each col-group (lex) ----
    #pragma unroll
    for (int m_ = 1; m_ <= 8; m_ <<= 1) {
        #pragma unroll
        for (int g = 0; g < 2; ++g)
            #pragma unroll
            for (int r = 0; r < 4; ++r) {
                float ov1 = __shfl_xor(v1[g][r], m_, 16); int ok1 = __shfl_xor(k1[g][r], m_, 16);
                float ov2 = __shfl_xor(v2[g][r], m_, 16); int ok2 = __shfl_xor(k2[g][r], m_, 16);
                if (ov1 < v1[g][r] || (ov1 == v1[g][r] && ok1 < k1[g][r])) {
                    if (v1[g][r] < ov2 || (v1[g][r] == ov2 && k1[g][r] < ok2)) { v2[g][r] = v1[g][r]; k2[g][r] = k1[g][r]; }
                    else { v2[g][r] = ov2; k2[g][r] = ok2; }
                    v1[g][r] = ov1; k1[g][r] = ok1;
                } else if (ov1 < v2[g][r] || (ov1 == v2[g][r] && ok1 < k2[g][r])) {
                    v2[g][r] = ov1; k2[g][r] = ok1;
                }
            }
    }
    if (ln == 0) {
        #pragma unroll
        for (int g = 0; g < 2; ++g)
            #pragma unroll
            for (int r = 0; r < 4; ++r) {
                int row_local = rw * 32 + g * 16 + quad * 4 + r;
                s_res[part][row_local] = make_float4(v1[g][r], v2[g][r],
                                                     __int_as_float(k1[g][r]),
                                                     __int_as_float(k2[g][r]));
            }
    }
    __syncthreads();

    // ---- per-row finalize: merge partitions, fp64 re-decide, exact fp32 dist ----
    if (t < ROWS_PB) {
        int rowg = rowblock + t;
        bool valid = rowg < rows;
        int rowc = valid ? rowg : rows - 1;

        float fv1 = INFINITY, fv2 = INFINITY;
        int   fk1 = 0x7fffffff, fk2 = 0x7fffffff;
        #pragma unroll
        for (int p = 0; p < 2; ++p) {
            float4 pt = s_res[p][t];
            float pv1 = pt.x, pv2 = pt.y;
            int   pk1 = __float_as_int(pt.z), pk2 = __float_as_int(pt.w);
            if (pv1 < fv1 || (pv1 == fv1 && pk1 < fk1)) { fv2 = fv1; fk2 = fk1; fv1 = pv1; fk1 = pk1; }
            else if (pv1 < fv2 || (pv1 == fv2 && pk1 < fk2)) { fv2 = pv1; fk2 = pk1; }
            if (pv2 < fv1 || (pv2 == fv1 && pk2 < fk1)) { fv2 = fv1; fk2 = fk1; fv1 = pv2; fk1 = pk2; }
            else if (pv2 < fv2 || (pv2 == fv2 && pk2 < fk2)) { fv2 = pv2; fk2 = pk2; }
        }

        const float* xr = x + (size_t)rowc * C;
        // rs in R1 float4 order
        float sx = 0.f, sy = 0.f, sz = 0.f, sw = 0.f;
        {
            const float4* xp = (const float4*)xr;
            #pragma unroll
            for (int i = 0; i < C / 4; ++i) {
                float4 v = xp[i];
                sx += v.x * v.x; sy += v.y * v.y;
                sz += v.z * v.z; sw += v.w * v.w;
            }
        }
        const float rs = (sx + sy) + (sz + sw);

        int kfin = fk1;
        bool switched = false;
        double qwin = 0.0;
        if (fv2 - fv1 < EPS_TRIG) {
            const float* c1p = cb + (size_t)fk1 * C;
            const float* c2p = cb + (size_t)fk2 * C;
            double dot1 = 0.0, cq1 = 0.0, dot2 = 0.0, cq2 = 0.0;
            #pragma unroll 8
            for (int cc = 0; cc < C; ++cc) {
                const double xv  = (double)xr[cc];
                const double cv1 = (double)c1p[cc];
                const double cv2 = (double)c2p[cc];
                dot1 += xv * cv1;  cq1 += cv1 * cv1;
                dot2 += xv * cv2;  cq2 += cv2 * cv2;
            }
            const double q1 = cq1 - 2.0 * dot1;
            const double q2 = cq2 - 2.0 * dot2;
            if (q2 < q1 || (q2 == q1 && fk2 < fk1)) { kfin = fk2; switched = true; qwin = q2; }
        }

        // exact fp32 distance for the final index (R1 chain order)
        const float* cp = cb + (size_t)kfin * C;
        float a = 0.f;
        #pragma unroll 16
        for (int cc = 0; cc < C; ++cc) a = fmaf(xr[cc], cp[cc], a);
        float d = (rs + cq[kfin]) - 2.f * a;
        if (switched) d = (float)((double)rs + qwin);

        if (valid) {
            out_fidx[rowg] = (float)kfin;
            out_idx[rowg]  = (float)kfin;
            out_dist[rowg] = d;
        }
        s_kf[t] = kfin;
    }
    __syncthreads();

    // ---- gather codes: 8 rows per iteration, 32 threads per row ----
    #pragma unroll 1
    for (int rr = 0; rr < ROWS_PB; rr += 8) {
        int r = rr + (t >> 5);
        int rowg2 = rowblock + r;
        if (rowg2 < rows) {
            const float4* src = (const float4*)(cb + (size_t)s_kf[r] * C);
            float4* dst = (float4*)(out_codes + (size_t)rowg2 * C);
            dst[t & 31] = src[t & 31];
        }
    }
}

// ---------------- fallback (R1 kernel, needs no workspace) ----------------
__global__ __launch_bounds__(TPB, 1)
void vq_nearest_fallback(const float* __restrict__ x,
                         const float* __restrict__ cb,
                         float* __restrict__ out_codes,
                         float* __restrict__ out_fidx,
                         float* __restrict__ out_idx,
                         float* __restrict__ out_dist,
                         int rows)
{
    __shared__ float s_cbsq[KCODES];
    const int t = threadIdx.x;
    for (int k = t; k < KCODES; k += TPB) {
        const float4* cp = (const float4*)(cb + (size_t)k * C);
        float sx = 0.f, sy = 0.f, sz = 0.f, sw = 0.f;
        #pragma unroll
        for (int i = 0; i < C / 4; ++i) {
            float4 v = cp[i];
            sx += v.x * v.x; sy += v.y * v.y; sz += v.z * v.z; sw += v.w * v.w;
        }
        s_cbsq[k] = (sx + sy) + (sz + sw);
    }
    __syncthreads();
    const int row = blockIdx.x * TPB + t;
    if (row >= rows) return;
    float xr[C];
    {
        const float4* xp = (const float4*)(x + (size_t)row * C);
        #pragma unroll
        for (int i = 0; i < C / 4; ++i) {
            float4 v = xp[i];
            xr[4*i+0] = v.x; xr[4*i+1] = v.y; xr[4*i+2] = v.z; xr[4*i+3] = v.w;
        }
    }
    float rs;
    {
        float sx = 0.f, sy = 0.f, sz = 0.f, sw = 0.f;
        #pragma unroll
        for (int i = 0; i < C / 4; ++i) {
            sx += xr[4*i+0]*xr[4*i+0]; sy += xr[4*i+1]*xr[4*i+1];
            sz += xr[4*i+2]*xr[4*i+2]; sw += xr[4*i+3]*xr[4*i+3];
        }
        rs = (sx + sy) + (sz + sw);
    }
    float v1 = INFINITY, v2 = INFINITY; int k1 = 0, k2 = 0;
    #pragma unroll 1
    for (int k0 = 0; k0 < KCODES; k0 += 4) {
        const float* c0 = cb + (size_t)k0 * C;
        float a0 = 0.f, a1 = 0.f, a2 = 0.f, a3 = 0.f;
        #pragma unroll
        for (int c = 0; c < C; ++c) {
            const float xc = xr[c];
            a0 = fmaf(xc, c0[c], a0);
            a1 = fmaf(xc, c0[C + c], a1);
            a2 = fmaf(xc, c0[2*C + c], a2);
            a3 = fmaf(xc, c0[3*C + c], a3);
        }
        const float d0 = (rs + s_cbsq[k0+0]) - 2.f * a0;
        const float d1 = (rs + s_cbsq[k0+1]) - 2.f * a1;
        const float d2 = (rs + s_cbsq[k0+2]) - 2.f * a2;
        const float d3 = (rs + s_cbsq[k0+3]) - 2.f * a3;
        #define UPDF(dv, ki)                                                 \
            if ((dv) < v1)      { v2 = v1; k2 = k1; v1 = (dv); k1 = (ki); } \
            else if ((dv) < v2) { v2 = (dv); k2 = (ki); }
        UPDF(d0, k0+0); UPDF(d1, k0+1); UPDF(d2, k0+2); UPDF(d3, k0+3);
        #undef UPDF
    }
    if (v2 - v1 < 0.125f) {
        const float* c1p = cb + (size_t)k1 * C;
        const float* c2p = cb + (size_t)k2 * C;
        double dot1 = 0.0, cq1 = 0.0, dot2 = 0.0, cq2 = 0.0;
        #pragma unroll 8
        for (int c = 0; c < C; ++c) {
            const double xc = (double)xr[c];
            const double cv1 = (double)c1p[c];
            const double cv2 = (double)c2p[c];
            dot1 += xc * cv1; cq1 += cv1 * cv1;
            dot2 += xc * cv2; cq2 += cv2 * cv2;
        }
        const double qa = cq1 - 2.0 * dot1;
        const double qb = cq2 - 2.0 * dot2;
        if (qb < qa || (qb == qa && k2 < k1)) { k1 = k2; v1 = (float)((double)rs + qb); }
    }
    {
        const float4* src = (const float4*)(cb + (size_t)k1 * C);
        float4* dst = (float4*)(out_codes + (size_t)row * C);
        #pragma unroll
        for (int i = 0; i < C / 4; ++i) dst[i] = src[i];
        out_fidx[row] = (float)k1;
        out_idx[row]  = (float)k1;
        out_dist[row] = v1;
    }
}

extern "C" void kernel_launch(void* const* d_in, const int* in_sizes, int n_in,
                              void* d_out, int out_size, void* d_ws, size_t ws_size,
                              hipStream_t stream) {
    const float* x  = (const float*)d_in[0];
    const float* cb = (const float*)d_in[1];
    const int rows = in_sizes[0] / C;   // 65536

    float* out       = (float*)d_out;
    float* out_codes = out;                          // rows*C
    float* out_fidx  = out + (size_t)rows * C;       // rows
    float* out_idx   = out_fidx + rows;              // rows
    float* out_dist  = out_idx + rows;               // rows

    // workspace layout: cbh (256KB), cbl (256KB), cq (4KB)
    const size_t cbh_off = 0;
    const size_t cbl_off = (size_t)KCODES * C * sizeof(uint16_t);
    const size_t cq_off  = cbl_off * 2;
    const size_t need    = cq_off + KCODES * sizeof(float);

    if (ws_size >= need) {
        uint16_t* cbh = (uint16_t*)((char*)d_ws + cbh_off);
        uint16_t* cbl = (uint16_t*)((char*)d_ws + cbl_off);
        float*    cq  = (float*)((char*)d_ws + cq_off);

        cb_split_kernel<<<(KCODES * C + TPB - 1) / TPB, TPB, 0, stream>>>(cb, cbh, cbl);
        cbsq_kernel<<<(KCODES + TPB - 1) / TPB, TPB, 0, stream>>>(cb, cq);

        const int grid = (rows + ROWS_PB - 1) / ROWS_PB;   // 1024
        vq_mfma3_kernel<<<grid, TPB, 0, stream>>>(x, cb, cbh, cbl, cq,
                                                  out_codes, out_fidx, out_idx,
                                                  out_dist, rows);
    } else {
        const int rowblocks = (rows + TPB - 1) / TPB;
        vq_nearest_fallback<<<rowblocks, TPB, 0, stream>>>(x, cb, out_codes, out_fidx,
                                                           out_idx, out_dist, rows);
    }
}